// Round 1
// baseline (144.403 us; speedup 1.0000x reference)
//
#include <hip/hip_runtime.h>

// LIF neuron forward: per neuron (B*C*N = 2,097,152), scan T=32 timesteps.
//   decay = 1 - 1/TAU = 0.5 ; VTH = 1.0
//   v = v*decay + x_t ; s = (v - VTH > 0) ; v = v - s*VTH
// T is innermost and contiguous in both x and out -> each thread owns one
// neuron's 128B run; 8x float4 load / store, scan in registers.

constexpr int T = 32;

__global__ __launch_bounds__(256) void lif_fwd_kernel(const float* __restrict__ x,
                                                      float* __restrict__ out,
                                                      int n_neurons) {
    int i = blockIdx.x * blockDim.x + threadIdx.x;
    if (i >= n_neurons) return;

    const float4* __restrict__ xin = reinterpret_cast<const float4*>(x + (size_t)i * T);
    float4* __restrict__ so        = reinterpret_cast<float4*>(out + (size_t)i * T);

    // Load all 8 float4 (32 timesteps) up front so the 8 loads pipeline.
    float4 xv0 = xin[0], xv1 = xin[1], xv2 = xin[2], xv3 = xin[3];
    float4 xv4 = xin[4], xv5 = xin[5], xv6 = xin[6], xv7 = xin[7];

    float v = 0.0f;

    auto step = [&v](float xt) -> float {
        v = v * 0.5f + xt;
        float s = (v > 1.0f) ? 1.0f : 0.0f;
        v -= s;
        return s;
    };

    float4 s0, s1, s2, s3, s4, s5, s6, s7;
    s0.x = step(xv0.x); s0.y = step(xv0.y); s0.z = step(xv0.z); s0.w = step(xv0.w);
    s1.x = step(xv1.x); s1.y = step(xv1.y); s1.z = step(xv1.z); s1.w = step(xv1.w);
    s2.x = step(xv2.x); s2.y = step(xv2.y); s2.z = step(xv2.z); s2.w = step(xv2.w);
    s3.x = step(xv3.x); s3.y = step(xv3.y); s3.z = step(xv3.z); s3.w = step(xv3.w);
    s4.x = step(xv4.x); s4.y = step(xv4.y); s4.z = step(xv4.z); s4.w = step(xv4.w);
    s5.x = step(xv5.x); s5.y = step(xv5.y); s5.z = step(xv5.z); s5.w = step(xv5.w);
    s6.x = step(xv6.x); s6.y = step(xv6.y); s6.z = step(xv6.z); s6.w = step(xv6.w);
    s7.x = step(xv7.x); s7.y = step(xv7.y); s7.z = step(xv7.z); s7.w = step(xv7.w);

    so[0] = s0; so[1] = s1; so[2] = s2; so[3] = s3;
    so[4] = s4; so[5] = s5; so[6] = s6; so[7] = s7;
}

extern "C" void kernel_launch(void* const* d_in, const int* in_sizes, int n_in,
                              void* d_out, int out_size, void* d_ws, size_t ws_size,
                              hipStream_t stream) {
    const float* x = (const float*)d_in[0];
    float* out = (float*)d_out;
    int n_neurons = in_sizes[0] / T;   // 16*128*1024 = 2,097,152
    const int block = 256;
    int grid = (n_neurons + block - 1) / block;
    lif_fwd_kernel<<<grid, block, 0, stream>>>(x, out, n_neurons);
}

// Round 2
// 105.969 us; speedup vs baseline: 1.3627x; 1.3627x over previous
//
#include <hip/hip_runtime.h>

// LIF forward, LDS-transposed for coalescing.
// x, out: [B*C*N, T] f32, T=32 contiguous. Per neuron:
//   v = v*0.5 + x_t ; s = (v>1) ; v -= s
// Stage-in coalesced -> LDS (pad ROW=33 words, conflict-free strided reads)
// -> per-thread scan in registers -> spikes back to own LDS row ->
// coalesced stage-out.

constexpr int T = 32;
constexpr int BLOCK = 256;
constexpr int ROW = T + 1;  // +1 float pad: LDS bank = (tid + t) % 32 -> 2-way (free)

__global__ __launch_bounds__(BLOCK) void lif_fwd_lds(const float* __restrict__ x,
                                                     float* __restrict__ out,
                                                     int n_neurons) {
    __shared__ float lds[BLOCK * ROW];
    const int tid = threadIdx.x;
    const long long nbase = (long long)blockIdx.x * BLOCK;

    if (nbase + BLOCK <= n_neurons) {
        const float4* __restrict__ xin = reinterpret_cast<const float4*>(x + nbase * T);
        float4* __restrict__ so        = reinterpret_cast<float4*>(out + nbase * T);

        // Stage in: 2048 float4 per block, coalesced; scatter to padded rows.
        #pragma unroll
        for (int k = 0; k < 8; ++k) {
            const int f = tid + k * BLOCK;      // float4 index in block chunk
            const float4 v4 = xin[f];
            const int n = f >> 3, p = f & 7;    // neuron row, quarter within row
            float* dst = &lds[n * ROW + p * 4];
            dst[0] = v4.x; dst[1] = v4.y; dst[2] = v4.z; dst[3] = v4.w;
        }
        __syncthreads();

        // Scan own neuron (row reads: bank (tid+t)%32, conflict-free).
        float v = 0.0f;
        float* row = &lds[tid * ROW];
        #pragma unroll
        for (int t = 0; t < T; ++t) {
            const float xt = row[t];
            v = v * 0.5f + xt;
            const float s = (v > 1.0f) ? 1.0f : 0.0f;
            v -= s;
            row[t] = s;                          // thread-private row: no hazard
        }
        __syncthreads();

        // Stage out: gather from padded rows, coalesced float4 stores.
        #pragma unroll
        for (int k = 0; k < 8; ++k) {
            const int f = tid + k * BLOCK;
            const int n = f >> 3, p = f & 7;
            const float* src = &lds[n * ROW + p * 4];
            so[f] = make_float4(src[0], src[1], src[2], src[3]);
        }
    } else {
        // Tail block (not hit for 2^21 neurons, kept for robustness):
        const long long i = nbase + tid;
        if (i < n_neurons) {
            const float* xi = x + i * T;
            float* oi = out + i * T;
            float v = 0.0f;
            #pragma unroll
            for (int t = 0; t < T; ++t) {
                v = v * 0.5f + xi[t];
                const float s = (v > 1.0f) ? 1.0f : 0.0f;
                v -= s;
                oi[t] = s;
            }
        }
    }
}

extern "C" void kernel_launch(void* const* d_in, const int* in_sizes, int n_in,
                              void* d_out, int out_size, void* d_ws, size_t ws_size,
                              hipStream_t stream) {
    const float* x = (const float*)d_in[0];
    float* out = (float*)d_out;
    const int n_neurons = in_sizes[0] / T;      // 16*128*1024 = 2,097,152
    const int grid = (n_neurons + BLOCK - 1) / BLOCK;
    lif_fwd_lds<<<grid, BLOCK, 0, stream>>>(x, out, n_neurons);
}

// Round 4
// 81.576 us; speedup vs baseline: 1.7702x; 1.2990x over previous
//
#include <hip/hip_runtime.h>

// LIF forward, wave-private LDS transpose, barrier-free.
// x, out: [B*C*N, T] f32, T=32 contiguous.
//   v = v*0.5 + x_t ; s = (v>1) ; v -= s
// Each wave owns 64 neurons: batched coalesced float4 loads -> scatter to
// wave-private padded LDS rows -> per-lane scan (spikes packed into a 32-bit
// register mask, no LDS round trip) -> shfl-transposed coalesced nt stores.

typedef float f32x4 __attribute__((ext_vector_type(4)));  // clang vector: ok for nontemporal builtins

constexpr int T = 32;
constexpr int BLOCK = 256;
constexpr int WAVES = BLOCK / 64;
constexpr int ROW = T + 1;   // bank = (lane + t) % 32 on scan reads -> 2-way (free)

__global__ __launch_bounds__(BLOCK) void lif_fwd(const float* __restrict__ x,
                                                 float* __restrict__ out,
                                                 int n_neurons) {
    __shared__ float lds[WAVES * 64 * ROW];
    const int tid  = threadIdx.x;
    const int lane = tid & 63;
    const int w    = tid >> 6;
    float* __restrict__ wlds = &lds[w * 64 * ROW];

    const long long nb = (long long)blockIdx.x * BLOCK + (long long)w * 64; // wave's first neuron

    if (nb + 64 <= n_neurons) {
        const f32x4* __restrict__ xin = reinterpret_cast<const f32x4*>(x + nb * T);
        f32x4* __restrict__ so        = reinterpret_cast<f32x4*>(out + nb * T);

        // 1) Batched coalesced loads: 8x dwordx4 in flight.
        f32x4 r[8];
        #pragma unroll
        for (int k = 0; k < 8; ++k) r[k] = xin[64 * k + lane];

        // 2) Scatter to wave-private padded rows (2-way bank alias max).
        #pragma unroll
        for (int k = 0; k < 8; ++k) {
            const int f = 64 * k + lane;
            const int g = f >> 3, p = f & 7;
            float* dst = &wlds[g * ROW + p * 4];
            dst[0] = r[k].x; dst[1] = r[k].y; dst[2] = r[k].z; dst[3] = r[k].w;
        }
        // Wave-private data: same-wave ds_write->ds_read ordered by lgkmcnt,
        // no __syncthreads needed.

        // 3) Scan own neuron; pack spikes into a register bitmask.
        float v = 0.0f;
        unsigned mask = 0;
        const float* __restrict__ row = &wlds[lane * ROW];
        #pragma unroll
        for (int t = 0; t < T; ++t) {
            v = v * 0.5f + row[t];
            const bool fire = (v > 1.0f);
            mask |= (unsigned)fire << t;
            v -= fire ? 1.0f : 0.0f;
        }

        // 4) Transposed coalesced stores: lane l writes float4 f = 64k+lane,
        //    i.e. neuron g = 8k + (lane>>3), quarter p = lane&7. Fetch that
        //    neuron's mask via shfl, expand 4 bits -> float4, nt store.
        const int p = lane & 7;
        #pragma unroll
        for (int k = 0; k < 8; ++k) {
            const int src = 8 * k + (lane >> 3);
            const unsigned m = (unsigned)__shfl((int)mask, src);
            const unsigned bits = m >> (4 * p);
            f32x4 o;
            o.x = (bits & 1u) ? 1.0f : 0.0f;
            o.y = (bits & 2u) ? 1.0f : 0.0f;
            o.z = (bits & 4u) ? 1.0f : 0.0f;
            o.w = (bits & 8u) ? 1.0f : 0.0f;
            __builtin_nontemporal_store(o, &so[64 * k + lane]);
        }
    } else {
        // Tail (not hit for 2^21 neurons): scalar per-thread fallback.
        const long long i = nb + lane;
        if (i < n_neurons) {
            const float* xi = x + i * T;
            float* oi = out + i * T;
            float v = 0.0f;
            #pragma unroll
            for (int t = 0; t < T; ++t) {
                v = v * 0.5f + xi[t];
                const float s = (v > 1.0f) ? 1.0f : 0.0f;
                v -= s;
                oi[t] = s;
            }
        }
    }
}

extern "C" void kernel_launch(void* const* d_in, const int* in_sizes, int n_in,
                              void* d_out, int out_size, void* d_ws, size_t ws_size,
                              hipStream_t stream) {
    const float* x = (const float*)d_in[0];
    float* out = (float*)d_out;
    const int n_neurons = in_sizes[0] / T;   // 16*128*1024 = 2,097,152
    const int grid = (n_neurons + BLOCK - 1) / BLOCK;
    lif_fwd<<<grid, BLOCK, 0, stream>>>(x, out, n_neurons);
}